// Round 7
// baseline (183144.666 us; speedup 1.0000x reference)
//
#include <hip/hip_runtime.h>
#include <cstdint>

// XLA CPU emits unfused mul/add (no fast-math, no contraction). hipcc defaults
// to -ffp-contract=fast -> must disable to mirror rounding exactly.
#pragma clang fp contract(off)

#define HH 50
#define SORB 64
#define NSAMP 4096
#define TOT (SORB * NSAMP)
#define RSLOTS 128
#define RSTRIDE 56   // floats per ring row: [0..49] h, [50] seq word
#define SPIN_FUEL (1 << 16)   // safety net: bounded spins (hang -> wrong answer)

typedef __attribute__((ext_vector_type(2))) float v2f;
typedef __attribute__((ext_vector_type(4))) float v4f;

// ---- XLA CPU EmitFastTanh (llvm_ir/math_ops.cc), with_fma = false ----
__device__ __forceinline__ float xla_tanh(float x) {
  const float kClamp = 7.90531110763549805f;
  float ax = fabsf(x);
  float xc = fminf(fmaxf(x, -kClamp), kClamp);
  float x2 = xc * xc;
  float p = -2.76076847742355e-16f;
  p = x2 * p + 2.00018790482477e-13f;
  p = x2 * p + -8.60467152213735e-11f;
  p = x2 * p + 5.12229709037114e-08f;
  p = x2 * p + 1.48572235717979e-05f;
  p = x2 * p + 6.37261928875436e-04f;
  p = x2 * p + 4.89352455891786e-03f;
  p = xc * p;
  float q = 1.19825839466702e-06f;
  q = x2 * q + 1.18534705686654e-04f;
  q = x2 * q + 2.26843463243900e-03f;
  q = x2 * q + 4.89352518554385e-03f;
  float r = p / q;
  return (ax < 0.0004f) ? x : r;
}

// XLA HLO kLogistic: 0.5 + 0.5 * tanh(0.5 * x)
__device__ __forceinline__ float xla_logistic(float x) {
  return 0.5f + 0.5f * xla_tanh(x * 0.5f);
}

// correctly-rounded f32 exp (matches glibc expf)
__device__ __forceinline__ float exp_cr(float x) {
  return (float)exp((double)x);
}

// ---- bit-exact Threefry-2x32 (20 rounds), as in jax/_src/prng.py ----
__device__ __forceinline__ void tf2x32(uint32_t k0, uint32_t k1,
                                       uint32_t c0, uint32_t c1,
                                       uint32_t& o0, uint32_t& o1) {
  uint32_t k2 = k0 ^ k1 ^ 0x1BD11BDAu;
  uint32_t x0 = c0 + k0, x1 = c1 + k1;
#define TF_R(d) { x0 += x1; x1 = (x1 << (d)) | (x1 >> (32 - (d))); x1 ^= x0; }
#define TF_GA TF_R(13) TF_R(15) TF_R(26) TF_R(6)
#define TF_GB TF_R(17) TF_R(29) TF_R(16) TF_R(24)
  TF_GA; x0 += k1; x1 += k2 + 1u;
  TF_GB; x0 += k2; x1 += k0 + 2u;
  TF_GA; x0 += k0; x1 += k1 + 3u;
  TF_GB; x0 += k1; x1 += k2 + 4u;
  TF_GA; x0 += k2; x1 += k0 + 5u;
#undef TF_GB
#undef TF_GA
#undef TF_R
  o0 = x0; o1 = x1;
}

// u_{i,j} = jax.random.uniform(fold_in(key(42), i), (4096,))[j]
__device__ __forceinline__ float u_for_cell(int cc) {
  int ii = cc >> 12;
  int jj = cc & (NSAMP - 1);
  uint32_t k0, k1;
  tf2x32(0u, 42u, 0u, (uint32_t)ii, k0, k1);   // fold_in: threefry(key, [0,i])
  uint32_t b0, b1;
  tf2x32(k0, k1, 0u, (uint32_t)jj, b0, b1);
  uint32_t bits = b0 ^ b1;                      // partitionable counter scheme
  return __uint_as_float((bits >> 9) | 0x3f800000u) - 1.0f;
}

// Load one 50-float row as 25 NAMED v2f locals (no arrays -> no SROA failure,
// register-candidates for sure).
#define LW(W, wp) do {                                                       \
  W##0  = v2f{(wp)[0],  (wp)[1]};  W##1  = v2f{(wp)[2],  (wp)[3]};           \
  W##2  = v2f{(wp)[4],  (wp)[5]};  W##3  = v2f{(wp)[6],  (wp)[7]};           \
  W##4  = v2f{(wp)[8],  (wp)[9]};  W##5  = v2f{(wp)[10], (wp)[11]};          \
  W##6  = v2f{(wp)[12], (wp)[13]}; W##7  = v2f{(wp)[14], (wp)[15]};          \
  W##8  = v2f{(wp)[16], (wp)[17]}; W##9  = v2f{(wp)[18], (wp)[19]};          \
  W##10 = v2f{(wp)[20], (wp)[21]}; W##11 = v2f{(wp)[22], (wp)[23]};          \
  W##12 = v2f{(wp)[24], (wp)[25]}; W##13 = v2f{(wp)[26], (wp)[27]};          \
  W##14 = v2f{(wp)[28], (wp)[29]}; W##15 = v2f{(wp)[30], (wp)[31]};          \
  W##16 = v2f{(wp)[32], (wp)[33]}; W##17 = v2f{(wp)[34], (wp)[35]};          \
  W##18 = v2f{(wp)[36], (wp)[37]}; W##19 = v2f{(wp)[38], (wp)[39]};          \
  W##20 = v2f{(wp)[40], (wp)[41]}; W##21 = v2f{(wp)[42], (wp)[43]};          \
  W##22 = v2f{(wp)[44], (wp)[45]}; W##23 = v2f{(wp)[46], (wp)[47]};          \
  W##24 = v2f{(wp)[48], (wp)[49]};                                           \
} while (0)

// XLA RowMajorMatrixVectorProduct, vector width 8, no FMA — pairwise form,
// bit-identical to the proven R1 scalar tree. NOTE: W##24 must not be
// followed by '.x' directly (pp-number '24.x' would absorb the member);
// bind through a local first.
#define XDOT(res, W) do {                                                    \
  v2f A0 = W##0 * h0, A1 = W##1 * h1, A2 = W##2 * h2, A3 = W##3 * h3;        \
  A0 = A0 + W##4  * h4;  A1 = A1 + W##5  * h5;                               \
  A2 = A2 + W##6  * h6;  A3 = A3 + W##7  * h7;                               \
  A0 = A0 + W##8  * h8;  A1 = A1 + W##9  * h9;                               \
  A2 = A2 + W##10 * h10; A3 = A3 + W##11 * h11;                              \
  A0 = A0 + W##12 * h12; A1 = A1 + W##13 * h13;                              \
  A2 = A2 + W##14 * h14; A3 = A3 + W##15 * h15;                              \
  A0 = A0 + W##16 * h16; A1 = A1 + W##17 * h17;                              \
  A2 = A2 + W##18 * h18; A3 = A3 + W##19 * h19;                              \
  A0 = A0 + W##20 * h20; A1 = A1 + W##21 * h21;                              \
  A2 = A2 + W##22 * h22; A3 = A3 + W##23 * h23;                              \
  v2f S0 = A0 + A2, S1 = A1 + A3, T = S0 + S1;                               \
  v2f Wl_ = W##24;                                                           \
  float d_ = T.x + T.y;                                                      \
  d_ = d_ + Wl_.x * h24.x;                                                   \
  d_ = d_ + Wl_.y * h24.y;                                                   \
  res = d_;                                                                  \
} while (0)

extern "C" __global__ void __launch_bounds__(128, 1)
ARSampler_59244778881183_kernel(const float* __restrict__ w_ih,
                                const float* __restrict__ w_hh,
                                const float* __restrict__ b_ih,
                                const float* __restrict__ b_hh,
                                const float* __restrict__ fc_w,
                                const float* __restrict__ fc_b,
                                int* __restrict__ out) {
  __shared__ __align__(16) float ring[RSLOTS][RSTRIDE];   // 28672 B
  __shared__ float sh_nu[NSAMP];                          // 16384 B
  __shared__ unsigned char sh_bits[2][NSAMP];             // 8192 B
  __shared__ unsigned int sh_done;

  const int t = threadIdx.x;
  const int lane = t & 63;

  // ---- LDS init by BOTH waves, then one barrier (kills stale-LDS races) ----
  if (t < 64) {
    for (int s = lane; s < RSLOTS; s += 64)
      ring[s][HH] = __uint_as_float(~0u);      // seq words: can't alias targets
    if (lane < HH) ring[RSLOTS - 1][lane] = 0.0f;  // h(-1) = 0
  } else {
    if (lane == 0) sh_done = 0u;
    for (int q = lane; q < NSAMP; q += 64) sh_nu[q] = 0.0f;
  }
  __syncthreads();

  if (t < 64) {
    // ================= chain wave =================
    const int tr = (lane < HH) ? lane : 0;   // clamped row id for idle lanes

    // 75 NAMED v2f weight locals (150 floats) — the R6 experiment.
    v2f wA0, wA1, wA2, wA3, wA4, wA5, wA6, wA7, wA8, wA9, wA10, wA11, wA12,
        wA13, wA14, wA15, wA16, wA17, wA18, wA19, wA20, wA21, wA22, wA23, wA24;
    v2f wB0, wB1, wB2, wB3, wB4, wB5, wB6, wB7, wB8, wB9, wB10, wB11, wB12,
        wB13, wB14, wB15, wB16, wB17, wB18, wB19, wB20, wB21, wB22, wB23, wB24;
    v2f wC0, wC1, wC2, wC3, wC4, wC5, wC6, wC7, wC8, wC9, wC10, wC11, wC12,
        wC13, wC14, wC15, wC16, wC17, wC18, wC19, wC20, wC21, wC22, wC23, wC24;
    LW(wA, w_hh + tr * HH);
    LW(wB, w_hh + (tr + 50) * HH);
    LW(wC, w_hh + (tr + 100) * HH);

    const float bhr = b_hh[tr], bhz = b_hh[tr + 50], bhn = b_hh[tr + 100];
    const float xrb = b_ih[tr], xzb = b_ih[tr + 50], xnb = b_ih[tr + 100];
    const float xr0 = w_ih[tr * 2 + 0] + xrb;
    const float xr1 = w_ih[tr * 2 + 1] + xrb;
    const float xz0 = w_ih[(tr + 50) * 2 + 0] + xzb;
    const float xz1 = w_ih[(tr + 50) * 2 + 1] + xzb;
    const float xn0 = w_ih[(tr + 100) * 2 + 0] + xnb;
    const float xn1 = w_ih[(tr + 100) * 2 + 1] + xnb;
    float hold = 0.0f;

    volatile unsigned int* donep = &sh_done;

    for (int c = 0; c < TOT; ++c) {
      const int i = c >> 12;
      const int j = c & (NSAMP - 1);

      // backpressure vs sampler (ring + sh_bits reuse), once per 64 cells
      if ((c & 63) == 0 && c >= RSLOTS) {
        int fuel = SPIN_FUEL;
        while (*donep < (unsigned)(c - 64) && --fuel)
          __builtin_amdgcn_s_sleep(2);
        asm volatile("" ::: "memory");   // don't hoist sh_bits/ring reads above
      }

      // broadcast-read h from the slot written at the end of cell c-1
      const float* rp = ring[(c + RSLOTS - 1) & (RSLOTS - 1)];
      v4f f0 = *(const v4f*)(rp + 0);
      v4f f1 = *(const v4f*)(rp + 4);
      v4f f2 = *(const v4f*)(rp + 8);
      v4f f3 = *(const v4f*)(rp + 12);
      v4f f4 = *(const v4f*)(rp + 16);
      v4f f5 = *(const v4f*)(rp + 20);
      v4f f6 = *(const v4f*)(rp + 24);
      v4f f7 = *(const v4f*)(rp + 28);
      v4f f8 = *(const v4f*)(rp + 32);
      v4f f9 = *(const v4f*)(rp + 36);
      v4f f10 = *(const v4f*)(rp + 40);
      v4f f11 = *(const v4f*)(rp + 44);
      v4f f12 = *(const v4f*)(rp + 48);
      v2f h0 = v2f{f0.x, f0.y}, h1 = v2f{f0.z, f0.w};
      v2f h2 = v2f{f1.x, f1.y}, h3 = v2f{f1.z, f1.w};
      v2f h4 = v2f{f2.x, f2.y}, h5 = v2f{f2.z, f2.w};
      v2f h6 = v2f{f3.x, f3.y}, h7 = v2f{f3.z, f3.w};
      v2f h8 = v2f{f4.x, f4.y}, h9 = v2f{f4.z, f4.w};
      v2f h10 = v2f{f5.x, f5.y}, h11 = v2f{f5.z, f5.w};
      v2f h12 = v2f{f6.x, f6.y}, h13 = v2f{f6.z, f6.w};
      v2f h14 = v2f{f7.x, f7.y}, h15 = v2f{f7.z, f7.w};
      v2f h16 = v2f{f8.x, f8.y}, h17 = v2f{f8.z, f8.w};
      v2f h18 = v2f{f9.x, f9.y}, h19 = v2f{f9.z, f9.w};
      v2f h20 = v2f{f10.x, f10.y}, h21 = v2f{f10.z, f10.w};
      v2f h22 = v2f{f11.x, f11.y}, h23 = v2f{f11.z, f11.w};
      v2f h24 = v2f{f12.x, f12.y};

      // x-projection select (wave-uniform i; broadcast byte read of prev bit)
      float xr, xz, xn;
      if (i == 0) {
        xr = xrb; xz = xzb; xn = xnb;
      } else {
        unsigned b = sh_bits[(i - 1) & 1][j];
        xr = b ? xr1 : xr0;
        xz = b ? xz1 : xz0;
        xn = b ? xn1 : xn0;
      }

      // GEMV rows t, t+50, t+100 (all consumed locally, never leave the lane)
      float dr, dz, dn;
      XDOT(dr, wA);
      XDOT(dz, wB);
      XDOT(dn, wC);
      const float ghr = dr + bhr;
      const float ghz = dz + bhz;
      const float ghn = dn + bhn;

      // GRU gates (exact op order of the proven R1 kernel)
      const float r = xla_logistic(xr + ghr);
      const float z = xla_logistic(xz + ghz);
      const float rhn = r * ghn;
      const float n = xla_tanh(xn + rhn);
      const float omz = 1.0f - z;
      const float hnew = omz * n + z * hold;
      hold = hnew;

      // combined write: lanes<50 write h, lanes>=50 write the seq word — one
      // ds_write_b32, so seq-visible implies h-visible (in-order DS pipe).
      const int wi = (lane < HH) ? lane : HH;
      const float wd = (lane < HH) ? hnew : __uint_as_float((unsigned)c);
      ring[c & (RSLOTS - 1)][wi] = wd;
    }
  } else {
    // ================= sampler wave (async, no barriers) =================
    float fw0[HH], fw1[HH];
#pragma unroll
    for (int k = 0; k < HH; ++k) {
      fw0[k] = fc_w[k];
      fw1[k] = fc_w[HH + k];
    }
    const float fb0 = fc_b[0], fb1 = fc_b[1];

    for (int B = 0; B < TOT; B += 64) {
      const int cc = B + lane;
      const int ii = B >> 12;                 // wave-uniform (4096 % 64 == 0)
      const int jj = cc & (NSAMP - 1);

      // wait until the chain published cell B+63 (seq values unique per cell)
      {
        const unsigned target = (unsigned)(B + 63);
        volatile unsigned int* sp =
            (volatile unsigned int*)&ring[(B + 63) & (RSLOTS - 1)][HH];
        int fuel = SPIN_FUEL;
        while (*sp != target && --fuel) __builtin_amdgcn_s_sleep(2);
        __builtin_amdgcn_s_sleep(1);   // cover sub-instruction LDS commit skew
        asm volatile("s_waitcnt lgkmcnt(0)" ::: "memory");
      }

      // logits: chunked v4f consumption, exact sequential k=0..49 FMA order
      const float* op = ring[cc & (RSLOTS - 1)];
      float l0 = 0.0f, l1 = 0.0f;
#pragma unroll
      for (int m = 0; m < 12; ++m) {
        v4f f = *(const v4f*)(op + 4 * m);
        l0 = fmaf(f.x, fw0[4 * m + 0], l0);
        l1 = fmaf(f.x, fw1[4 * m + 0], l1);
        l0 = fmaf(f.y, fw0[4 * m + 1], l0);
        l1 = fmaf(f.y, fw1[4 * m + 1], l1);
        l0 = fmaf(f.z, fw0[4 * m + 2], l0);
        l1 = fmaf(f.z, fw1[4 * m + 2], l1);
        l0 = fmaf(f.w, fw0[4 * m + 3], l0);
        l1 = fmaf(f.w, fw1[4 * m + 3], l1);
      }
      {
        v2f f = *(const v2f*)(op + 48);
        l0 = fmaf(f.x, fw0[48], l0);
        l1 = fmaf(f.x, fw1[48], l1);
        l0 = fmaf(f.y, fw0[49], l0);
        l1 = fmaf(f.y, fw1[49], l1);
      }
      l0 = l0 + fb0;
      l1 = l1 + fb1;

      // sqrt(softmax)
      const float mx = fmaxf(l0, l1);
      const float e0 = exp_cr(l0 - mx);
      const float e1 = exp_cr(l1 - mx);
      const float se = e0 + e1;
      float o0 = sqrtf(e0 / se);
      float o1 = sqrtf(e1 / se);

      const float nuo = sh_nu[jj];
      if (ii >= SORB / 2) {
        const float fi = (float)ii;
        const float ndown = fi - nuo;
        const float ad = ((31.0f - ndown) >= 0.0f) ? 1.0f : 0.0f;
        const float au = ((31.0f - nuo) >= 0.0f) ? 1.0f : 0.0f;
        const float m0 = o0 * ad;
        const float m1 = o1 * au;
        float nr = sqrtf(m0 * m0 + m1 * m1);
        nr = fmaxf(nr, 1e-30f);
        o0 = m0 / nr;
        o1 = m1 / nr;
      }
      const float den = fmaxf(o0 + o1, 1e-30f);
      const float p0 = o0 / den;
      const float u = u_for_cell(cc);
      const int s = (u >= p0) ? 1 : 0;

      sh_nu[jj] = nuo + (float)s;
      sh_bits[ii & 1][jj] = (unsigned char)s;
      out[jj * SORB + ii] = s;   // samples.T

      // publish progress AFTER the bits/nu writes (in-order DS pipe; the asm
      // memory clobber keeps the compiler from sinking the stores past it)
      asm volatile("" ::: "memory");
      *(volatile unsigned int*)&sh_done = (unsigned)(B + 64);
    }
  }
}

// Clock probe: a separate dispatch whose rocprof row directly measures the
// effective shader clock. 262144 x 16 DEPENDENT v_fma_f32 = 4.19M FMAs at
// 4 cyc dep latency (m07) = 16.78M cycles. dur ~= 7.0 ms @ 2.4 GHz,
// ~= 16.8 ms @ 1.0 GHz. Result stored to d_ws (not validated) to stop DCE.
extern "C" __global__ void __launch_bounds__(64, 1)
ARSampler_clockprobe(float* __restrict__ sink) {
  if (threadIdx.x == 0) {
    float a = 1.0f;
    const float m = 1.0000001f, cc = 1e-9f;
    for (int it = 0; it < 262144; ++it) {
#pragma unroll
      for (int k = 0; k < 16; ++k) a = fmaf(a, m, cc);
    }
    *(volatile float*)sink = a;
  }
}

extern "C" void kernel_launch(void* const* d_in, const int* in_sizes, int n_in,
                              void* d_out, int out_size, void* d_ws, size_t ws_size,
                              hipStream_t stream) {
  (void)in_sizes; (void)n_in; (void)out_size; (void)ws_size;
  const float* w_ih = (const float*)d_in[0];
  const float* w_hh = (const float*)d_in[1];
  const float* b_ih = (const float*)d_in[2];
  const float* b_hh = (const float*)d_in[3];
  const float* fc_w = (const float*)d_in[4];
  const float* fc_b = (const float*)d_in[5];
  hipLaunchKernelGGL(ARSampler_59244778881183_kernel, dim3(1), dim3(128), 0, stream,
                     w_ih, w_hh, b_ih, b_hh, fc_w, fc_b, (int*)d_out);
  hipLaunchKernelGGL(ARSampler_clockprobe, dim3(1), dim3(64), 0, stream,
                     (float*)d_ws);
}

// Round 8
// 173241.101 us; speedup vs baseline: 1.0572x; 1.0572x over previous
//
#include <hip/hip_runtime.h>
#include <cstdint>

// XLA CPU emits unfused mul/add (no fast-math, no contraction). hipcc defaults
// to -ffp-contract=fast -> must disable to mirror rounding exactly.
#pragma clang fp contract(off)

#define HH 50
#define SORB 64
#define NSAMP 4096
#define TOT (SORB * NSAMP)
#define RSLOTS 128
#define RSTRIDE 56   // floats per ring row: [0..49] h, [50] seq word
#define SPIN_FUEL (1 << 16)   // safety net: bounded spins (hang -> wrong answer)

typedef __attribute__((ext_vector_type(2))) float v2f;
typedef __attribute__((ext_vector_type(4))) float v4f;

// ---- XLA CPU EmitFastTanh (llvm_ir/math_ops.cc), with_fma = false ----
__device__ __forceinline__ float xla_tanh(float x) {
  const float kClamp = 7.90531110763549805f;
  float ax = fabsf(x);
  float xc = fminf(fmaxf(x, -kClamp), kClamp);
  float x2 = xc * xc;
  float p = -2.76076847742355e-16f;
  p = x2 * p + 2.00018790482477e-13f;
  p = x2 * p + -8.60467152213735e-11f;
  p = x2 * p + 5.12229709037114e-08f;
  p = x2 * p + 1.48572235717979e-05f;
  p = x2 * p + 6.37261928875436e-04f;
  p = x2 * p + 4.89352455891786e-03f;
  p = xc * p;
  float q = 1.19825839466702e-06f;
  q = x2 * q + 1.18534705686654e-04f;
  q = x2 * q + 2.26843463243900e-03f;
  q = x2 * q + 4.89352518554385e-03f;
  float r = p / q;
  return (ax < 0.0004f) ? x : r;
}

// XLA HLO kLogistic: 0.5 + 0.5 * tanh(0.5 * x)
__device__ __forceinline__ float xla_logistic(float x) {
  return 0.5f + 0.5f * xla_tanh(x * 0.5f);
}

// correctly-rounded f32 exp (matches glibc expf)
__device__ __forceinline__ float exp_cr(float x) {
  return (float)exp((double)x);
}

// ---- bit-exact Threefry-2x32 (20 rounds), as in jax/_src/prng.py ----
__device__ __forceinline__ void tf2x32(uint32_t k0, uint32_t k1,
                                       uint32_t c0, uint32_t c1,
                                       uint32_t& o0, uint32_t& o1) {
  uint32_t k2 = k0 ^ k1 ^ 0x1BD11BDAu;
  uint32_t x0 = c0 + k0, x1 = c1 + k1;
#define TF_R(d) { x0 += x1; x1 = (x1 << (d)) | (x1 >> (32 - (d))); x1 ^= x0; }
#define TF_GA TF_R(13) TF_R(15) TF_R(26) TF_R(6)
#define TF_GB TF_R(17) TF_R(29) TF_R(16) TF_R(24)
  TF_GA; x0 += k1; x1 += k2 + 1u;
  TF_GB; x0 += k2; x1 += k0 + 2u;
  TF_GA; x0 += k0; x1 += k1 + 3u;
  TF_GB; x0 += k1; x1 += k2 + 4u;
  TF_GA; x0 += k2; x1 += k0 + 5u;
#undef TF_GB
#undef TF_GA
#undef TF_R
  o0 = x0; o1 = x1;
}

// u_{i,j} = jax.random.uniform(fold_in(key(42), i), (4096,))[j]
__device__ __forceinline__ float u_for_cell(int cc) {
  int ii = cc >> 12;
  int jj = cc & (NSAMP - 1);
  uint32_t k0, k1;
  tf2x32(0u, 42u, 0u, (uint32_t)ii, k0, k1);   // fold_in: threefry(key, [0,i])
  uint32_t b0, b1;
  tf2x32(k0, k1, 0u, (uint32_t)jj, b0, b1);
  uint32_t bits = b0 ^ b1;                      // partitionable counter scheme
  return __uint_as_float((bits >> 9) | 0x3f800000u) - 1.0f;
}

// Opaque identity pin: the value becomes an inline-asm output, which LLVM
// cannot rematerialize from the original global load -> it must stay live
// in VGPRs across the whole 262144-iteration loop (the R8 experiment).
#define PIN(W) do {                                            \
  double p_ = __builtin_bit_cast(double, W);                   \
  asm volatile("" : "+v"(p_));                                 \
  W = __builtin_bit_cast(v2f, p_);                             \
} while (0)

// Load one 50-float row as 25 NAMED v2f locals.
#define LW(W, wp) do {                                                       \
  W##0  = v2f{(wp)[0],  (wp)[1]};  W##1  = v2f{(wp)[2],  (wp)[3]};           \
  W##2  = v2f{(wp)[4],  (wp)[5]};  W##3  = v2f{(wp)[6],  (wp)[7]};           \
  W##4  = v2f{(wp)[8],  (wp)[9]};  W##5  = v2f{(wp)[10], (wp)[11]};          \
  W##6  = v2f{(wp)[12], (wp)[13]}; W##7  = v2f{(wp)[14], (wp)[15]};          \
  W##8  = v2f{(wp)[16], (wp)[17]}; W##9  = v2f{(wp)[18], (wp)[19]};          \
  W##10 = v2f{(wp)[20], (wp)[21]}; W##11 = v2f{(wp)[22], (wp)[23]};          \
  W##12 = v2f{(wp)[24], (wp)[25]}; W##13 = v2f{(wp)[26], (wp)[27]};          \
  W##14 = v2f{(wp)[28], (wp)[29]}; W##15 = v2f{(wp)[30], (wp)[31]};          \
  W##16 = v2f{(wp)[32], (wp)[33]}; W##17 = v2f{(wp)[34], (wp)[35]};          \
  W##18 = v2f{(wp)[36], (wp)[37]}; W##19 = v2f{(wp)[38], (wp)[39]};          \
  W##20 = v2f{(wp)[40], (wp)[41]}; W##21 = v2f{(wp)[42], (wp)[43]};          \
  W##22 = v2f{(wp)[44], (wp)[45]}; W##23 = v2f{(wp)[46], (wp)[47]};          \
  W##24 = v2f{(wp)[48], (wp)[49]};                                           \
} while (0)

#define PINROW(W) do {                                                       \
  PIN(W##0);  PIN(W##1);  PIN(W##2);  PIN(W##3);  PIN(W##4);                 \
  PIN(W##5);  PIN(W##6);  PIN(W##7);  PIN(W##8);  PIN(W##9);                 \
  PIN(W##10); PIN(W##11); PIN(W##12); PIN(W##13); PIN(W##14);                \
  PIN(W##15); PIN(W##16); PIN(W##17); PIN(W##18); PIN(W##19);                \
  PIN(W##20); PIN(W##21); PIN(W##22); PIN(W##23); PIN(W##24);                \
} while (0)

// XLA RowMajorMatrixVectorProduct, vector width 8, no FMA — pairwise form,
// bit-identical to the proven R1 scalar tree. NOTE: W##24 must not be
// followed by '.x' directly (pp-number '24.x' would absorb the member);
// bind through a local first.
#define XDOT(res, W) do {                                                    \
  v2f A0 = W##0 * h0, A1 = W##1 * h1, A2 = W##2 * h2, A3 = W##3 * h3;        \
  A0 = A0 + W##4  * h4;  A1 = A1 + W##5  * h5;                               \
  A2 = A2 + W##6  * h6;  A3 = A3 + W##7  * h7;                               \
  A0 = A0 + W##8  * h8;  A1 = A1 + W##9  * h9;                               \
  A2 = A2 + W##10 * h10; A3 = A3 + W##11 * h11;                              \
  A0 = A0 + W##12 * h12; A1 = A1 + W##13 * h13;                              \
  A0 = A0 + W##16 * h16; A1 = A1 + W##17 * h17;                              \
  A2 = A2 + W##14 * h14; A3 = A3 + W##15 * h15;                              \
  A2 = A2 + W##18 * h18; A3 = A3 + W##19 * h19;                              \
  A0 = A0 + W##20 * h20; A1 = A1 + W##21 * h21;                              \
  A2 = A2 + W##22 * h22; A3 = A3 + W##23 * h23;                              \
  v2f S0 = A0 + A2, S1 = A1 + A3, T = S0 + S1;                               \
  v2f Wl_ = W##24;                                                           \
  float d_ = T.x + T.y;                                                      \
  d_ = d_ + Wl_.x * h24.x;                                                   \
  d_ = d_ + Wl_.y * h24.y;                                                   \
  res = d_;                                                                  \
} while (0)

extern "C" __global__ void
__attribute__((amdgpu_flat_work_group_size(128, 128), amdgpu_waves_per_eu(1, 1)))
ARSampler_59244778881183_kernel(const float* __restrict__ w_ih,
                                const float* __restrict__ w_hh,
                                const float* __restrict__ b_ih,
                                const float* __restrict__ b_hh,
                                const float* __restrict__ fc_w,
                                const float* __restrict__ fc_b,
                                int* __restrict__ out) {
  __shared__ __align__(16) float ring[RSLOTS][RSTRIDE];   // 28672 B
  __shared__ float sh_nu[NSAMP];                          // 16384 B
  __shared__ unsigned char sh_bits[2][NSAMP];             // 8192 B
  __shared__ unsigned int sh_done;

  const int t = threadIdx.x;
  const int lane = t & 63;

  // ---- LDS init by BOTH waves, then one barrier (kills stale-LDS races) ----
  if (t < 64) {
    for (int s = lane; s < RSLOTS; s += 64)
      ring[s][HH] = __uint_as_float(~0u);      // seq words: can't alias targets
    if (lane < HH) ring[RSLOTS - 1][lane] = 0.0f;  // h(-1) = 0
  } else {
    if (lane == 0) sh_done = 0u;
    for (int q = lane; q < NSAMP; q += 64) sh_nu[q] = 0.0f;
  }
  __syncthreads();

  if (t < 64) {
    // ================= chain wave =================
    const int tr = (lane < HH) ? lane : 0;   // clamped row id for idle lanes

    v2f wA0, wA1, wA2, wA3, wA4, wA5, wA6, wA7, wA8, wA9, wA10, wA11, wA12,
        wA13, wA14, wA15, wA16, wA17, wA18, wA19, wA20, wA21, wA22, wA23, wA24;
    v2f wB0, wB1, wB2, wB3, wB4, wB5, wB6, wB7, wB8, wB9, wB10, wB11, wB12,
        wB13, wB14, wB15, wB16, wB17, wB18, wB19, wB20, wB21, wB22, wB23, wB24;
    v2f wC0, wC1, wC2, wC3, wC4, wC5, wC6, wC7, wC8, wC9, wC10, wC11, wC12,
        wC13, wC14, wC15, wC16, wC17, wC18, wC19, wC20, wC21, wC22, wC23, wC24;
    LW(wA, w_hh + tr * HH);
    LW(wB, w_hh + (tr + 50) * HH);
    LW(wC, w_hh + (tr + 100) * HH);
    // R8: opaque pins — weights become non-rematerializable asm outputs.
    PINROW(wA);
    PINROW(wB);
    PINROW(wC);

    const float bhr = b_hh[tr], bhz = b_hh[tr + 50], bhn = b_hh[tr + 100];
    const float xrb = b_ih[tr], xzb = b_ih[tr + 50], xnb = b_ih[tr + 100];
    const float xr0 = w_ih[tr * 2 + 0] + xrb;
    const float xr1 = w_ih[tr * 2 + 1] + xrb;
    const float xz0 = w_ih[(tr + 50) * 2 + 0] + xzb;
    const float xz1 = w_ih[(tr + 50) * 2 + 1] + xzb;
    const float xn0 = w_ih[(tr + 100) * 2 + 0] + xnb;
    const float xn1 = w_ih[(tr + 100) * 2 + 1] + xnb;
    float hold = 0.0f;

    volatile unsigned int* donep = &sh_done;

    for (int c = 0; c < TOT; ++c) {
      const int i = c >> 12;
      const int j = c & (NSAMP - 1);

      // backpressure vs sampler (ring + sh_bits reuse), once per 64 cells
      if ((c & 63) == 0 && c >= RSLOTS) {
        int fuel = SPIN_FUEL;
        while (*donep < (unsigned)(c - 64) && --fuel)
          __builtin_amdgcn_s_sleep(2);
        asm volatile("" ::: "memory");   // don't hoist sh_bits/ring reads above
      }

      // broadcast-read h from the slot written at the end of cell c-1
      const float* rp = ring[(c + RSLOTS - 1) & (RSLOTS - 1)];
      v4f f0 = *(const v4f*)(rp + 0);
      v4f f1 = *(const v4f*)(rp + 4);
      v4f f2 = *(const v4f*)(rp + 8);
      v4f f3 = *(const v4f*)(rp + 12);
      v4f f4 = *(const v4f*)(rp + 16);
      v4f f5 = *(const v4f*)(rp + 20);
      v4f f6 = *(const v4f*)(rp + 24);
      v4f f7 = *(const v4f*)(rp + 28);
      v4f f8 = *(const v4f*)(rp + 32);
      v4f f9 = *(const v4f*)(rp + 36);
      v4f f10 = *(const v4f*)(rp + 40);
      v4f f11 = *(const v4f*)(rp + 44);
      v4f f12 = *(const v4f*)(rp + 48);
      v2f h0 = v2f{f0.x, f0.y}, h1 = v2f{f0.z, f0.w};
      v2f h2 = v2f{f1.x, f1.y}, h3 = v2f{f1.z, f1.w};
      v2f h4 = v2f{f2.x, f2.y}, h5 = v2f{f2.z, f2.w};
      v2f h6 = v2f{f3.x, f3.y}, h7 = v2f{f3.z, f3.w};
      v2f h8 = v2f{f4.x, f4.y}, h9 = v2f{f4.z, f4.w};
      v2f h10 = v2f{f5.x, f5.y}, h11 = v2f{f5.z, f5.w};
      v2f h12 = v2f{f6.x, f6.y}, h13 = v2f{f6.z, f6.w};
      v2f h14 = v2f{f7.x, f7.y}, h15 = v2f{f7.z, f7.w};
      v2f h16 = v2f{f8.x, f8.y}, h17 = v2f{f8.z, f8.w};
      v2f h18 = v2f{f9.x, f9.y}, h19 = v2f{f9.z, f9.w};
      v2f h20 = v2f{f10.x, f10.y}, h21 = v2f{f10.z, f10.w};
      v2f h22 = v2f{f11.x, f11.y}, h23 = v2f{f11.z, f11.w};
      v2f h24 = v2f{f12.x, f12.y};

      // x-projection select (wave-uniform i; broadcast byte read of prev bit)
      float xr, xz, xn;
      if (i == 0) {
        xr = xrb; xz = xzb; xn = xnb;
      } else {
        unsigned b = sh_bits[(i - 1) & 1][j];
        xr = b ? xr1 : xr0;
        xz = b ? xz1 : xz0;
        xn = b ? xn1 : xn0;
      }

      // GEMV rows t, t+50, t+100 (all consumed locally, never leave the lane)
      float dr, dz, dn;
      XDOT(dr, wA);
      XDOT(dz, wB);
      XDOT(dn, wC);
      const float ghr = dr + bhr;
      const float ghz = dz + bhz;
      const float ghn = dn + bhn;

      // GRU gates (exact op order of the proven R1 kernel)
      const float r = xla_logistic(xr + ghr);
      const float z = xla_logistic(xz + ghz);
      const float rhn = r * ghn;
      const float n = xla_tanh(xn + rhn);
      const float omz = 1.0f - z;
      const float hnew = omz * n + z * hold;
      hold = hnew;

      // combined write: lanes<50 write h, lanes>=50 write the seq word — one
      // ds_write_b32, so seq-visible implies h-visible (in-order DS pipe).
      const int wi = (lane < HH) ? lane : HH;
      const float wd = (lane < HH) ? hnew : __uint_as_float((unsigned)c);
      ring[c & (RSLOTS - 1)][wi] = wd;
    }
  } else {
    // ================= sampler wave (async, no barriers) =================
    float fw0[HH], fw1[HH];
#pragma unroll
    for (int k = 0; k < HH; ++k) {
      fw0[k] = fc_w[k];
      fw1[k] = fc_w[HH + k];
    }
    const float fb0 = fc_b[0], fb1 = fc_b[1];

    for (int B = 0; B < TOT; B += 64) {
      const int cc = B + lane;
      const int ii = B >> 12;                 // wave-uniform (4096 % 64 == 0)
      const int jj = cc & (NSAMP - 1);

      // wait until the chain published cell B+63 (seq values unique per cell)
      {
        const unsigned target = (unsigned)(B + 63);
        volatile unsigned int* sp =
            (volatile unsigned int*)&ring[(B + 63) & (RSLOTS - 1)][HH];
        int fuel = SPIN_FUEL;
        while (*sp != target && --fuel) __builtin_amdgcn_s_sleep(2);
        __builtin_amdgcn_s_sleep(1);   // cover sub-instruction LDS commit skew
        asm volatile("s_waitcnt lgkmcnt(0)" ::: "memory");
      }

      // logits: chunked v4f consumption, exact sequential k=0..49 FMA order
      const float* op = ring[cc & (RSLOTS - 1)];
      float l0 = 0.0f, l1 = 0.0f;
#pragma unroll
      for (int m = 0; m < 12; ++m) {
        v4f f = *(const v4f*)(op + 4 * m);
        l0 = fmaf(f.x, fw0[4 * m + 0], l0);
        l1 = fmaf(f.x, fw1[4 * m + 0], l1);
        l0 = fmaf(f.y, fw0[4 * m + 1], l0);
        l1 = fmaf(f.y, fw1[4 * m + 1], l1);
        l0 = fmaf(f.z, fw0[4 * m + 2], l0);
        l1 = fmaf(f.z, fw1[4 * m + 2], l1);
        l0 = fmaf(f.w, fw0[4 * m + 3], l0);
        l1 = fmaf(f.w, fw1[4 * m + 3], l1);
      }
      {
        v2f f = *(const v2f*)(op + 48);
        l0 = fmaf(f.x, fw0[48], l0);
        l1 = fmaf(f.x, fw1[48], l1);
        l0 = fmaf(f.y, fw0[49], l0);
        l1 = fmaf(f.y, fw1[49], l1);
      }
      l0 = l0 + fb0;
      l1 = l1 + fb1;

      // sqrt(softmax)
      const float mx = fmaxf(l0, l1);
      const float e0 = exp_cr(l0 - mx);
      const float e1 = exp_cr(l1 - mx);
      const float se = e0 + e1;
      float o0 = sqrtf(e0 / se);
      float o1 = sqrtf(e1 / se);

      const float nuo = sh_nu[jj];
      if (ii >= SORB / 2) {
        const float fi = (float)ii;
        const float ndown = fi - nuo;
        const float ad = ((31.0f - ndown) >= 0.0f) ? 1.0f : 0.0f;
        const float au = ((31.0f - nuo) >= 0.0f) ? 1.0f : 0.0f;
        const float m0 = o0 * ad;
        const float m1 = o1 * au;
        float nr = sqrtf(m0 * m0 + m1 * m1);
        nr = fmaxf(nr, 1e-30f);
        o0 = m0 / nr;
        o1 = m1 / nr;
      }
      const float den = fmaxf(o0 + o1, 1e-30f);
      const float p0 = o0 / den;
      const float u = u_for_cell(cc);
      const int s = (u >= p0) ? 1 : 0;

      sh_nu[jj] = nuo + (float)s;
      sh_bits[ii & 1][jj] = (unsigned char)s;
      out[jj * SORB + ii] = s;   // samples.T

      // publish progress AFTER the bits/nu writes (in-order DS pipe; the asm
      // memory clobber keeps the compiler from sinking the stores past it)
      asm volatile("" ::: "memory");
      *(volatile unsigned int*)&sh_done = (unsigned)(B + 64);
    }
  }
}

extern "C" void kernel_launch(void* const* d_in, const int* in_sizes, int n_in,
                              void* d_out, int out_size, void* d_ws, size_t ws_size,
                              hipStream_t stream) {
  (void)in_sizes; (void)n_in; (void)out_size; (void)d_ws; (void)ws_size;
  const float* w_ih = (const float*)d_in[0];
  const float* w_hh = (const float*)d_in[1];
  const float* b_ih = (const float*)d_in[2];
  const float* b_hh = (const float*)d_in[3];
  const float* fc_w = (const float*)d_in[4];
  const float* fc_b = (const float*)d_in[5];
  hipLaunchKernelGGL(ARSampler_59244778881183_kernel, dim3(1), dim3(128), 0, stream,
                     w_ih, w_hh, b_ih, b_hh, fc_w, fc_b, (int*)d_out);
}